// Round 1
// baseline (6135.483 us; speedup 1.0000x reference)
//
#include <hip/hip_runtime.h>
#include <stdint.h>

// Problem dims
#define Hh 256                 // hidden
#define Sd 128                 // batch (seq positions)
#define Nt 512                 // time steps per pass
#define NPASS 3
#define TSTEPS (NPASS*Nt)      // 1536
#define RBLK 16                // batch rows per workgroup
#define TPB 1024

typedef float f32x4 __attribute__((ext_vector_type(4)));
typedef __bf16 bf16x8 __attribute__((ext_vector_type(8)));
typedef unsigned short u16x8 __attribute__((ext_vector_type(8)));

#define HBUF_ELEMS (Nt*Sd*Hh)                    // ushorts per layer h-ring (16.7M)
#define WPACK_OFF  (2ull*(size_t)HBUF_ELEMS*2)   // 67,108,864 B
#define FLAGS_OFF  (WPACK_OFF + 2097152ull)      // +2MB packed weights

__device__ __forceinline__ unsigned short f2bf(float f) {
  unsigned u = __builtin_bit_cast(unsigned, f);
  u += 0x7FFFu + ((u >> 16) & 1u);               // RNE
  return (unsigned short)(u >> 16);
}

// ---------------- weight packing ----------------
// Packs [Wih;Whh] (layer l) into per-(wg,wave,ktile,lane) MFMA B-fragments, bf16.
// slot = (((l*4+g)*16 + w)*16 + kt)*64 + ln ; 8 bf16 per slot.
// value(j) = W[k = kt*32 + (ln>>4)*8 + j][col = q*256 + g*64 + jt*16 + (ln&15)]
__global__ void pack_w(const float* __restrict__ Wih0, const float* __restrict__ Whh0,
                       const float* __restrict__ Wih1, const float* __restrict__ Whh1,
                       unsigned short* __restrict__ wpack) {
  int id = blockIdx.x * 256 + threadIdx.x;       // 131072 total
  int ln = id & 63;
  int kt = (id >> 6) & 15;
  int w  = (id >> 10) & 15;
  int g  = (id >> 14) & 3;
  int l  = id >> 16;
  int q = w >> 2, jt = w & 3;
  int col = q*256 + g*64 + jt*16 + (ln & 15);
  int k0 = kt*32 + (ln >> 4)*8;
  const float* Wih = l ? Wih1 : Wih0;
  const float* Whh = l ? Whh1 : Whh0;
  const float* src = (k0 < 256) ? (Wih + (size_t)col*256 + k0)
                                : (Whh + (size_t)col*256 + (k0 - 256));
  u16x8 v;
#pragma unroll
  for (int j = 0; j < 8; ++j) v[j] = f2bf(src[j]);
  *(u16x8*)(wpack + (size_t)id * 8) = v;
}

// ---------------- data[0] = x copy ----------------
__global__ void copy_x(const float* __restrict__ x, float* __restrict__ out) {
  int id = blockIdx.x * 256 + threadIdx.x;       // 4,194,304 float4s
  int n  = id >> 13;
  int s  = (id >> 6) & 127;
  int h4 = id & 63;
  const float4 v = *(const float4*)(x + ((size_t)n*Sd + s)*Hh + h4*4);
  *(float4*)(out + ((size_t)n*(Sd*4) + s*4)*Hh + h4*4) = v;
}

// ---------------- persistent pipelined LSTM ----------------
// 64 blocks x 1024 threads. block b: r=b&7 (rowblock, ~XCD), l=(b>>3)>>2 (layer), g=(b>>3)&3 (col wg).
__global__ void __launch_bounds__(TPB) lstm_persist(
    const float* __restrict__ x,
    const float* __restrict__ bih0, const float* __restrict__ bhh0,
    const float* __restrict__ bih1, const float* __restrict__ bhh1,
    const unsigned short* __restrict__ wpack,
    unsigned short* __restrict__ hbuf,
    unsigned int* __restrict__ prog,
    float* __restrict__ out)
{
  const int b = blockIdx.x;
  const int r = b & 7;
  const int l = (b >> 3) >> 2;
  const int g = (b >> 3) & 3;
  const int tid = threadIdx.x;
  const int ln = tid & 63;
  const int w  = tid >> 6;

  __shared__ __align__(16) unsigned short Ain[RBLK * 256]; // input part (k 0..255), bf16, swizzled
  __shared__ __align__(16) unsigned short Ah [RBLK * 256]; // hidden part (k 256..511)
  __shared__ float gates[RBLK][260];                       // +pad: bank-conflict-free

  // --- weight fragments: 16 ktiles x bf16x8 = 64 VGPRs/lane, resident all kernel ---
  bf16x8 B[16];
  {
    const unsigned short* base = wpack + ((size_t)((l*4 + g)*16 + w)) * 8192 + (size_t)ln * 8;
#pragma unroll
    for (int kt = 0; kt < 16; ++kt) {
      u16x8 u = *(const u16x8*)(base + kt * 512);
      B[kt] = __builtin_bit_cast(bf16x8, u);
    }
  }

  // --- cell-phase identity: thread owns (row_c, hc) ---
  const int hc    = tid & 63;
  const int row_c = tid >> 6;           // == wave index
  const int sIdx  = r*RBLK + row_c;
  float bias[4];
  {
    const float* bi = l ? bih1 : bih0;
    const float* bh = l ? bhh1 : bhh0;
#pragma unroll
    for (int q = 0; q < 4; ++q) {
      int col = q*256 + g*64 + hc;
      bias[q] = bi[col] + bh[col];
    }
  }
  float cst = 0.f;                      // c-state, carries across all passes (matches reference)

  // --- MFMA fragment addressing ---
  const int row_f = ln & 15;
  const int kg16  = (ln >> 4) * 16;
  const int swz   = (row_f & 7) << 4;   // XOR swizzle: kills 16-way LDS read conflict

  // --- staging addressing: thread -> (row=wave, 8B chunk) ---
  const int srow   = tid >> 6;
  const int c8     = tid & 63;
  const int stAddr = srow * 512 + ((c8 * 8) ^ ((srow & 7) << 4));

  unsigned int* progSelf  = prog + (l*8 + r)*4;
  unsigned int* progOther = prog + ((1 - l)*8 + r)*4;
  const unsigned short* hbufL0 = hbuf;
  unsigned short* hbufSelf = hbuf + (size_t)l * HBUF_ELEMS;

  for (int T = 0; T < TSTEPS; ++T) {
    const int p = T >> 9;               // pass 0..2
    const int t = T & 511;

    // ===== phase A: input operand (overlaps peer-h latency) =====
    const bool needPollIn = (l == 1) || (p > 0);
    if (tid < 64 && needPollIn) {
      if (tid < 4) {
        unsigned tgt = (l == 1) ? (unsigned)(T + 1) : (unsigned)(T - 511);
        while (__hip_atomic_load(progOther + tid, __ATOMIC_RELAXED, __HIP_MEMORY_SCOPE_AGENT) < tgt)
          __builtin_amdgcn_s_sleep(1);
      }
      __builtin_amdgcn_fence(__ATOMIC_ACQUIRE, "agent");
    }
    __syncthreads();
    {
      const int s = r*RBLK + srow;
      if (l == 0) {
        const float* srcb = (p == 0)
          ? (x   + ((size_t)t*Sd + s)*Hh)
          : (out + ((size_t)t*(Sd*4) + s*4 + p)*Hh);   // data[p] written by L1 of pass p-1
        float4 v = *(const float4*)(srcb + c8*4);
        unsigned long long pk = (unsigned long long)f2bf(v.x)
          | ((unsigned long long)f2bf(v.y) << 16)
          | ((unsigned long long)f2bf(v.z) << 32)
          | ((unsigned long long)f2bf(v.w) << 48);
        *(unsigned long long*)((char*)Ain + stAddr) = pk;
      } else {
        const unsigned short* srcb = hbufL0 + ((size_t)t*Sd + s)*Hh;
        *(unsigned long long*)((char*)Ain + stAddr) = *(const unsigned long long*)(srcb + c8*4);
      }
    }
    __syncthreads();

    f32x4 acc0 = {0.f,0.f,0.f,0.f}, acc1 = {0.f,0.f,0.f,0.f};
#pragma unroll
    for (int kt = 0; kt < 8; kt += 2) {
      int off0 = row_f*512 + (( kt     *64 + kg16) ^ swz);
      int off1 = row_f*512 + (((kt + 1)*64 + kg16) ^ swz);
      u16x8 a0 = *(const u16x8*)((const char*)Ain + off0);
      u16x8 a1 = *(const u16x8*)((const char*)Ain + off1);
      acc0 = __builtin_amdgcn_mfma_f32_16x16x32_bf16(__builtin_bit_cast(bf16x8, a0), B[kt],     acc0, 0,0,0);
      acc1 = __builtin_amdgcn_mfma_f32_16x16x32_bf16(__builtin_bit_cast(bf16x8, a1), B[kt + 1], acc1, 0,0,0);
    }

    // ===== phase B: hidden operand (tight recurrence) =====
    if (tid < 64 && T > 0) {
      if (tid >= 4 && tid < 7) {
        unsigned gp = (unsigned)((g + (tid - 3)) & 3);
        while (__hip_atomic_load(progSelf + gp, __ATOMIC_RELAXED, __HIP_MEMORY_SCOPE_AGENT) < (unsigned)T)
          __builtin_amdgcn_s_sleep(1);
      }
      __builtin_amdgcn_fence(__ATOMIC_ACQUIRE, "agent");
    }
    __syncthreads();
    {
      const int s = r*RBLK + srow;
      if (T == 0) {
        *(unsigned long long*)((char*)Ah + stAddr) = 0ull;
      } else {
        const unsigned short* srcb = hbufSelf + ((size_t)((T - 1) & 511)*Sd + s)*Hh;
        *(unsigned long long*)((char*)Ah + stAddr) = *(const unsigned long long*)(srcb + c8*4);
      }
    }
    __syncthreads();
#pragma unroll
    for (int kt = 0; kt < 8; kt += 2) {
      int off0 = row_f*512 + (( kt     *64 + kg16) ^ swz);
      int off1 = row_f*512 + (((kt + 1)*64 + kg16) ^ swz);
      u16x8 a0 = *(const u16x8*)((const char*)Ah + off0);
      u16x8 a1 = *(const u16x8*)((const char*)Ah + off1);
      acc0 = __builtin_amdgcn_mfma_f32_16x16x32_bf16(__builtin_bit_cast(bf16x8, a0), B[8 + kt],     acc0, 0,0,0);
      acc1 = __builtin_amdgcn_mfma_f32_16x16x32_bf16(__builtin_bit_cast(bf16x8, a1), B[8 + kt + 1], acc1, 0,0,0);
    }
    // gates -> LDS (C layout: col=lane&15, row=(lane>>4)*4+j)
    {
      const int colb = (w >> 2)*64 + (w & 3)*16 + (ln & 15);
      const int rowb = (ln >> 4)*4;
#pragma unroll
      for (int j = 0; j < 4; ++j)
        gates[rowb + j][colb] = acc0[j] + acc1[j];
    }
    __syncthreads();
    // LSTM cell (gate order i,f,g,o), write h
    {
      float G0 = gates[row_c][hc]       + bias[0];
      float G1 = gates[row_c][64 + hc]  + bias[1];
      float G2 = gates[row_c][128 + hc] + bias[2];
      float G3 = gates[row_c][192 + hc] + bias[3];
      float gi = 1.f/(1.f + __expf(-G0));
      float gf = 1.f/(1.f + __expf(-G1));
      float gg = 1.f - 2.f/(1.f + __expf(2.f*G2));
      float go = 1.f/(1.f + __expf(-G3));
      cst = gf*cst + gi*gg;
      float th = 1.f - 2.f/(1.f + __expf(2.f*cst));
      float hv = go*th;
      hbufSelf[((size_t)t*Sd + sIdx)*Hh + g*64 + hc] = f2bf(hv);
      if (l == 1) out[((size_t)t*(Sd*4) + sIdx*4 + (p + 1))*Hh + g*64 + hc] = hv;
    }
    __syncthreads();
    if (tid == 0) {
      __builtin_amdgcn_fence(__ATOMIC_RELEASE, "agent");
      __hip_atomic_store(progSelf + g, (unsigned)(T + 1), __ATOMIC_RELAXED, __HIP_MEMORY_SCOPE_AGENT);
    }
  }
}

extern "C" void kernel_launch(void* const* d_in, const int* in_sizes, int n_in,
                              void* d_out, int out_size, void* d_ws, size_t ws_size,
                              hipStream_t stream) {
  const float* x    = (const float*)d_in[0];
  const float* Wih0 = (const float*)d_in[1];
  const float* Whh0 = (const float*)d_in[2];
  const float* bih0 = (const float*)d_in[3];
  const float* bhh0 = (const float*)d_in[4];
  const float* Wih1 = (const float*)d_in[5];
  const float* Whh1 = (const float*)d_in[6];
  const float* bih1 = (const float*)d_in[7];
  const float* bhh1 = (const float*)d_in[8];
  float* out = (float*)d_out;
  char* ws = (char*)d_ws;

  if (ws_size < FLAGS_OFF + 4096) return;  // need ~66 MB scratch

  unsigned short* hbuf  = (unsigned short*)ws;
  unsigned short* wpack = (unsigned short*)(ws + WPACK_OFF);
  unsigned int*   prog  = (unsigned int*)(ws + FLAGS_OFF);

  hipMemsetAsync(prog, 0, 256, stream);
  hipLaunchKernelGGL(pack_w, dim3(512), dim3(256), 0, stream, Wih0, Whh0, Wih1, Whh1, wpack);
  hipLaunchKernelGGL(copy_x, dim3(16384), dim3(256), 0, stream, x, out);
  hipLaunchKernelGGL(lstm_persist, dim3(64), dim3(TPB), 0, stream,
                     x, bih0, bhh0, bih1, bhh1, wpack, hbuf, prog, out);
}

// Round 2
// 4373.949 us; speedup vs baseline: 1.4027x; 1.4027x over previous
//
#include <hip/hip_runtime.h>
#include <stdint.h>

// Problem dims
#define Hh 256                 // hidden
#define Sd 128                 // batch (seq positions)
#define Nt 512                 // time steps per pass
#define NPASS 3
#define TSTEPS (NPASS*Nt)      // 1536
#define RBLK 16                // batch rows per workgroup
#define TPB 1024
#define POIS 0x7F80u           // bf16 +inf: |h|<1 so never a real h value
#define LEAD 192               // max L0 lead over L1 (must stay < 256-8-margin)

typedef float f32x4 __attribute__((ext_vector_type(4)));
typedef __bf16 bf16x8 __attribute__((ext_vector_type(8)));
typedef unsigned short u16x8 __attribute__((ext_vector_type(8)));

#define HBUF_ELEMS ((size_t)Nt*Sd*Hh)            // ushorts per layer h-ring
#define WPACK_OFF  (2ull*HBUF_ELEMS*2)           // 67,108,864 B
#define FLAGS_OFF  (WPACK_OFF + 2097152ull)      // +2MB packed weights

__device__ __forceinline__ unsigned short f2bf(float f) {
  unsigned u = __builtin_bit_cast(unsigned, f);
  u += 0x7FFFu + ((u >> 16) & 1u);               // RNE
  return (unsigned short)(u >> 16);
}

__device__ __forceinline__ bool hasPois(unsigned long long v) {
  return ((unsigned short)(v)       == (unsigned short)POIS) |
         ((unsigned short)(v >> 16) == (unsigned short)POIS) |
         ((unsigned short)(v >> 32) == (unsigned short)POIS) |
         ((unsigned short)(v >> 48) == (unsigned short)POIS);
}

// Relaxed agent-scope (cross-XCD coherent, L2-bypass) access helpers.
__device__ __forceinline__ unsigned long long ld8(const void* p) {
  return __hip_atomic_load((unsigned long long*)p, __ATOMIC_RELAXED, __HIP_MEMORY_SCOPE_AGENT);
}
__device__ __forceinline__ void st2c(void* p, unsigned short v) {
  __hip_atomic_store((unsigned short*)p, v, __ATOMIC_RELAXED, __HIP_MEMORY_SCOPE_AGENT);
}
__device__ __forceinline__ void st4c(void* p, float v) {
  __hip_atomic_store((float*)p, v, __ATOMIC_RELAXED, __HIP_MEMORY_SCOPE_AGENT);
}

// ---------------- weight packing (unchanged, verified) ----------------
__global__ void pack_w(const float* __restrict__ Wih0, const float* __restrict__ Whh0,
                       const float* __restrict__ Wih1, const float* __restrict__ Whh1,
                       unsigned short* __restrict__ wpack) {
  int id = blockIdx.x * 256 + threadIdx.x;       // 131072 total
  int ln = id & 63;
  int kt = (id >> 6) & 15;
  int w  = (id >> 10) & 15;
  int g  = (id >> 14) & 3;
  int l  = id >> 16;
  int q = w >> 2, jt = w & 3;
  int col = q*256 + g*64 + jt*16 + (ln & 15);
  int k0 = kt*32 + (ln >> 4)*8;
  const float* Wih = l ? Wih1 : Wih0;
  const float* Whh = l ? Whh1 : Whh0;
  const float* src = (k0 < 256) ? (Wih + (size_t)col*256 + k0)
                                : (Whh + (size_t)col*256 + (k0 - 256));
  u16x8 v;
#pragma unroll
  for (int j = 0; j < 8; ++j) v[j] = f2bf(src[j]);
  *(u16x8*)(wpack + (size_t)id * 8) = v;
}

// ---------------- data[0] = x copy ----------------
__global__ void copy_x(const float* __restrict__ x, float* __restrict__ out) {
  int id = blockIdx.x * 256 + threadIdx.x;       // 4,194,304 float4s
  int n  = id >> 13;
  int s  = (id >> 6) & 127;
  int h4 = id & 63;
  const float4 v = *(const float4*)(x + ((size_t)n*Sd + s)*Hh + h4*4);
  *(float4*)(out + ((size_t)n*(Sd*4) + s*4)*Hh + h4*4) = v;
}

// ---------------- ring pre-poison ----------------
__global__ void poison_hbuf(unsigned int* __restrict__ p) {
  size_t i = (size_t)blockIdx.x * 256 + threadIdx.x;   // 4,194,304 x 16B = 64MB
  uint4 v = make_uint4(0x7F807F80u, 0x7F807F80u, 0x7F807F80u, 0x7F807F80u);
  *(uint4*)(p + i*4) = v;
}

// ---------------- persistent pipelined LSTM ----------------
// 64 blocks x 1024 threads. block b: r=b&7 (rowblock, ~XCD), l=b>>5 (layer), g=(b>>3)&3 (col wg).
__global__ void __launch_bounds__(TPB) lstm_persist(
    const float* __restrict__ x,
    const float* __restrict__ bih0, const float* __restrict__ bhh0,
    const float* __restrict__ bih1, const float* __restrict__ bhh1,
    const unsigned short* __restrict__ wpack,
    unsigned short* __restrict__ hbuf,
    unsigned int* __restrict__ prog,
    float* __restrict__ out)
{
  const int b = blockIdx.x;
  const int r = b & 7;
  const int l = (b >> 3) >> 2;
  const int g = (b >> 3) & 3;
  const int tid = threadIdx.x;
  const int ln = tid & 63;
  const int w  = tid >> 6;

  __shared__ __align__(16) unsigned short Ain[RBLK * 256]; // input operand (k 0..255)
  __shared__ __align__(16) unsigned short Ah [RBLK * 256]; // hidden operand (k 256..511)
  __shared__ float gates[RBLK][260];                       // +pad: conflict-free

  // weight fragments: resident all kernel (verified layout)
  bf16x8 B[16];
  {
    const unsigned short* base = wpack + ((size_t)((l*4 + g)*16 + w)) * 8192 + (size_t)ln * 8;
#pragma unroll
    for (int kt = 0; kt < 16; ++kt) {
      u16x8 u = *(const u16x8*)(base + kt * 512);
      B[kt] = __builtin_bit_cast(bf16x8, u);
    }
  }

  const int hc    = tid & 63;
  const int row_c = tid >> 6;
  const int sIdx  = r*RBLK + row_c;
  float bias[4];
  {
    const float* bi = l ? bih1 : bih0;
    const float* bh = l ? bhh1 : bhh0;
#pragma unroll
    for (int q = 0; q < 4; ++q) {
      int col = q*256 + g*64 + hc;
      bias[q] = bi[col] + bh[col];
    }
  }
  float cst = 0.f;

  const int row_f = ln & 15;
  const int kg16  = (ln >> 4) * 16;
  const int swz   = (row_f & 7) << 4;

  const int srow   = tid >> 6;
  const int c8     = tid & 63;
  const int stAddr = srow * 512 + ((c8 * 8) ^ ((srow & 7) << 4));

  // flags: only L1 blocks publish (slot (8+r)*4+g); L0 polls all 4 of its r.
  unsigned int* flagL1 = prog + (8 + r) * 4;
  unsigned int* myFlag = prog + (8 + r) * 4 + g;
  const unsigned short* hbufL0 = hbuf;
  unsigned short* hbufSelf = hbuf + (size_t)l * HBUF_ELEMS;

  for (int T = 0; T < TSTEPS; ++T) {
    const int p = T >> 9;
    const int t = T & 511;
    const int s = r*RBLK + srow;

    // ===== A: stage both operands (poison-poll; no fences, no flag hop) =====
    unsigned long long ah8 = 0ull;
    const unsigned long long* ap =
      (const unsigned long long*)(hbufSelf + ((size_t)((T - 1) & 511)*Sd + s)*Hh + c8*4);
    if (l == 1) {
      const unsigned long long* ip =
        (const unsigned long long*)(hbufL0 + ((size_t)t*Sd + s)*Hh + c8*4);
      unsigned long long ain8 = ld8(ip);
      if (T > 0) ah8 = ld8(ap);
      while (hasPois(ain8)) { __builtin_amdgcn_s_sleep(1); ain8 = ld8(ip); }
      if (T > 0) while (hasPois(ah8)) { __builtin_amdgcn_s_sleep(1); ah8 = ld8(ap); }
      *(unsigned long long*)((char*)Ain + stAddr) = ain8;
    } else {
      float v0, v1, v2, v3;
      if (p == 0) {
        float4 xv = *(const float4*)(x + ((size_t)t*Sd + s)*Hh + c8*4);
        v0 = xv.x; v1 = xv.y; v2 = xv.z; v3 = xv.w;
      } else {
        // data[p] slice: written coherently by L1 (flag-guarded, >=311 steps old)
        const unsigned long long* op8 =
          (const unsigned long long*)(out + ((size_t)t*(Sd*4) + s*4 + p)*Hh + c8*4);
        unsigned long long o0 = ld8(op8);
        unsigned long long o1 = ld8(op8 + 1);
        v0 = __builtin_bit_cast(float, (unsigned)(o0 & 0xFFFFFFFFu));
        v1 = __builtin_bit_cast(float, (unsigned)(o0 >> 32));
        v2 = __builtin_bit_cast(float, (unsigned)(o1 & 0xFFFFFFFFu));
        v3 = __builtin_bit_cast(float, (unsigned)(o1 >> 32));
      }
      if (T > 0) {
        ah8 = ld8(ap);
        while (hasPois(ah8)) { __builtin_amdgcn_s_sleep(1); ah8 = ld8(ap); }
      }
      unsigned long long pk = (unsigned long long)f2bf(v0)
        | ((unsigned long long)f2bf(v1) << 16)
        | ((unsigned long long)f2bf(v2) << 32)
        | ((unsigned long long)f2bf(v3) << 48);
      *(unsigned long long*)((char*)Ain + stAddr) = pk;
    }
    *(unsigned long long*)((char*)Ah + stAddr) = ah8;

    // L0 lead-bound + out-slice pre-authorization (one step ahead; off critical path)
    if (l == 0 && tid < 4) {
      int need = T - LEAD;
      if (need > 0)
        while ((int)__hip_atomic_load(flagL1 + tid, __ATOMIC_RELAXED, __HIP_MEMORY_SCOPE_AGENT) < need)
          __builtin_amdgcn_s_sleep(1);
    }
    __syncthreads();

    // ===== C: 16 MFMA (input part then hidden part) =====
    f32x4 acc0 = {0.f,0.f,0.f,0.f}, acc1 = {0.f,0.f,0.f,0.f};
#pragma unroll
    for (int kt = 0; kt < 8; kt += 2) {
      int off0 = row_f*512 + (( kt     *64 + kg16) ^ swz);
      int off1 = row_f*512 + (((kt + 1)*64 + kg16) ^ swz);
      u16x8 a0 = *(const u16x8*)((const char*)Ain + off0);
      u16x8 a1 = *(const u16x8*)((const char*)Ain + off1);
      acc0 = __builtin_amdgcn_mfma_f32_16x16x32_bf16(__builtin_bit_cast(bf16x8, a0), B[kt],     acc0, 0,0,0);
      acc1 = __builtin_amdgcn_mfma_f32_16x16x32_bf16(__builtin_bit_cast(bf16x8, a1), B[kt + 1], acc1, 0,0,0);
    }
#pragma unroll
    for (int kt = 0; kt < 8; kt += 2) {
      int off0 = row_f*512 + (( kt     *64 + kg16) ^ swz);
      int off1 = row_f*512 + (((kt + 1)*64 + kg16) ^ swz);
      u16x8 a0 = *(const u16x8*)((const char*)Ah + off0);
      u16x8 a1 = *(const u16x8*)((const char*)Ah + off1);
      acc0 = __builtin_amdgcn_mfma_f32_16x16x32_bf16(__builtin_bit_cast(bf16x8, a0), B[8 + kt],     acc0, 0,0,0);
      acc1 = __builtin_amdgcn_mfma_f32_16x16x32_bf16(__builtin_bit_cast(bf16x8, a1), B[8 + kt + 1], acc1, 0,0,0);
    }
    {
      const int colb = (w >> 2)*64 + (w & 3)*16 + (ln & 15);
      const int rowb = (ln >> 4)*4;
#pragma unroll
      for (int j = 0; j < 4; ++j)
        gates[rowb + j][colb] = acc0[j] + acc1[j];
    }
    __syncthreads();

    // ===== F: LSTM cell + coherent stores (producer never waits) =====
    {
      float G0 = gates[row_c][hc]       + bias[0];
      float G1 = gates[row_c][64 + hc]  + bias[1];
      float G2 = gates[row_c][128 + hc] + bias[2];
      float G3 = gates[row_c][192 + hc] + bias[3];
      float gi = 1.f/(1.f + __expf(-G0));
      float gf = 1.f/(1.f + __expf(-G1));
      float gg = 1.f - 2.f/(1.f + __expf(2.f*G2));
      float go = 1.f/(1.f + __expf(-G3));
      cst = gf*cst + gi*gg;
      float th = 1.f - 2.f/(1.f + __expf(2.f*cst));
      float hv = go*th;
      st2c(hbufSelf + ((size_t)t*Sd + sIdx)*Hh + g*64 + hc, f2bf(hv));
      if (l == 1) st4c(out + ((size_t)t*(Sd*4) + sIdx*4 + (p + 1))*Hh + g*64 + hc, hv);
      // re-poison the slot we will write 256 steps from now (all lag bounds < 256)
      st2c(hbufSelf + ((size_t)((T + 256) & 511)*Sd + sIdx)*Hh + g*64 + hc, (unsigned short)POIS);
    }
    // L1 publishes progress every 8 steps (guards L0's out-slice reads + lead bound)
    if (l == 1 && (T & 7) == 7) {
      asm volatile("s_waitcnt vmcnt(0)" ::: "memory");
      __syncthreads();
      if (tid == 0)
        __hip_atomic_store(myFlag, (unsigned)(T + 1), __ATOMIC_RELAXED, __HIP_MEMORY_SCOPE_AGENT);
    }
  }
}

extern "C" void kernel_launch(void* const* d_in, const int* in_sizes, int n_in,
                              void* d_out, int out_size, void* d_ws, size_t ws_size,
                              hipStream_t stream) {
  const float* x    = (const float*)d_in[0];
  const float* Wih0 = (const float*)d_in[1];
  const float* Whh0 = (const float*)d_in[2];
  const float* bih0 = (const float*)d_in[3];
  const float* bhh0 = (const float*)d_in[4];
  const float* Wih1 = (const float*)d_in[5];
  const float* Whh1 = (const float*)d_in[6];
  const float* bih1 = (const float*)d_in[7];
  const float* bhh1 = (const float*)d_in[8];
  float* out = (float*)d_out;
  char* ws = (char*)d_ws;

  if (ws_size < FLAGS_OFF + 4096) return;  // need ~69 MB scratch

  unsigned short* hbuf  = (unsigned short*)ws;
  unsigned short* wpack = (unsigned short*)(ws + WPACK_OFF);
  unsigned int*   prog  = (unsigned int*)(ws + FLAGS_OFF);

  hipMemsetAsync(prog, 0, 256, stream);
  hipLaunchKernelGGL(poison_hbuf, dim3(16384), dim3(256), 0, stream, (unsigned int*)hbuf);
  hipLaunchKernelGGL(pack_w, dim3(512), dim3(256), 0, stream, Wih0, Whh0, Wih1, Whh1, wpack);
  hipLaunchKernelGGL(copy_x, dim3(16384), dim3(256), 0, stream, x, out);
  hipLaunchKernelGGL(lstm_persist, dim3(64), dim3(TPB), 0, stream,
                     x, bih0, bhh0, bih1, bhh1, wpack, hbuf, prog, out);
}